// Round 12
// baseline (544.725 us; speedup 1.0000x reference)
//
#include <hip/hip_runtime.h>
#include <hip/hip_bf16.h>
#include <math.h>

#define Bsz 4
#define Tsz 2048
#define Dsz 1024
#define Hn  16
#define HDs 64

typedef __attribute__((ext_vector_type(8))) short bf16x8;
typedef __attribute__((ext_vector_type(4))) float f32x4;

typedef const __attribute__((address_space(1))) void gvoid;
typedef __attribute__((address_space(3))) void lvoid;

__device__ __forceinline__ void async_copy16(const short* g, short* l) {
    __builtin_amdgcn_global_load_lds((gvoid*)g, (lvoid*)l, 16, 0, 0);
}

__device__ __forceinline__ short f2bf(float x) {
    __hip_bfloat16 h = __float2bfloat16(x);
    return *reinterpret_cast<short*>(&h);
}

// pack two fp32 -> two bf16 in one u32 (round-half-up via +0x8000, then
// v_perm grabs the high shorts). lo -> low half, hi -> high half.
__device__ __forceinline__ unsigned int pack_bf16(float hi, float lo) {
    unsigned int uh = __float_as_uint(hi) + 0x8000u;
    unsigned int ul = __float_as_uint(lo) + 0x8000u;
    return __builtin_amdgcn_perm(uh, ul, 0x07060302u);
}

// index into [b, h, t, kc] tensor given m = b*T + t, c = h*64 + kc
__device__ __forceinline__ size_t headed_idx(int m, int c) {
    int b = m >> 11, t = m & 2047, h = c >> 6, kc = c & 63;
    return (((size_t)(b * Hn + h) * Tsz + t) << 6) + kc;
}

// ---------------- LayerNorm: fp32 in, bf16 out -----------------------------
__global__ __launch_bounds__(256) void ln_kernel(const float* __restrict__ x,
                                                 const float* __restrict__ g,
                                                 const float* __restrict__ beta,
                                                 short* __restrict__ out)
{
    const int row = blockIdx.x;
    const float* xr = x + (size_t)row * Dsz;
    float v[4];
    float s = 0.f, s2 = 0.f;
#pragma unroll
    for (int i = 0; i < 4; ++i) {
        v[i] = xr[threadIdx.x + 256 * i];
        s += v[i];
        s2 += v[i] * v[i];
    }
#pragma unroll
    for (int off = 32; off; off >>= 1) {
        s  += __shfl_xor(s,  off);
        s2 += __shfl_xor(s2, off);
    }
    __shared__ float red[8];
    const int wave = threadIdx.x >> 6;
    if ((threadIdx.x & 63) == 0) { red[wave * 2] = s; red[wave * 2 + 1] = s2; }
    __syncthreads();
    s  = red[0] + red[2] + red[4] + red[6];
    s2 = red[1] + red[3] + red[5] + red[7];
    const float mu  = s * (1.f / Dsz);
    const float var = s2 * (1.f / Dsz) - mu * mu;
    const float rs  = rsqrtf(var + 1e-5f);
    short* orow = out + (size_t)row * Dsz;
#pragma unroll
    for (int i = 0; i < 4; ++i) {
        int col = threadIdx.x + 256 * i;
        orow[col] = f2bf((v[i] - mu) * rs * g[col] + beta[col]);
    }
}

// ---------------- fp32 [R][C] slice -> bf16 [C][R] (weight prep) -----------
__global__ __launch_bounds__(256) void transpose_cvt(
    const float* __restrict__ in, short* __restrict__ outp, int R, int C)
{
    __shared__ float tile[32][33];
    const int r0 = blockIdx.y * 32, c0 = blockIdx.x * 32;
    const size_t so = (size_t)blockIdx.z * R * C;
    const int tx = threadIdx.x & 31, ty = threadIdx.x >> 5;
    const float* ip = in + so;
    short* op = outp + so;
#pragma unroll
    for (int i = 0; i < 4; ++i)
        tile[ty + i * 8][tx] = ip[(size_t)(r0 + ty + i * 8) * C + c0 + tx];
    __syncthreads();
#pragma unroll
    for (int i = 0; i < 4; ++i)
        op[(size_t)(c0 + ty + i * 8) * R + r0 + tx] = f2bf(tile[tx][ty + i * 8]);
}

// QKV variant: z 0..47 selects Wq/Wk/Wv head slices, outputs contiguous.
__global__ __launch_bounds__(256) void transpose_cvt_qkv(
    const float* __restrict__ Wq, const float* __restrict__ Wk,
    const float* __restrict__ Wv, short* __restrict__ outp)
{
    __shared__ float tile[32][33];
    const int z = blockIdx.z;
    const float* in = (z < 16) ? Wq : (z < 32) ? Wk : Wv;
    const int zz = z & 15;
    const int r0 = blockIdx.y * 32, c0 = blockIdx.x * 32;
    const int tx = threadIdx.x & 31, ty = threadIdx.x >> 5;
    const float* ip = in + (size_t)zz * (1024 * 64);
    short* op = outp + (size_t)z * (1024 * 64);
#pragma unroll
    for (int i = 0; i < 4; ++i)
        tile[ty + i * 8][tx] = ip[(size_t)(r0 + ty + i * 8) * 64 + c0 + tx];
    __syncthreads();
#pragma unroll
    for (int i = 0; i < 4; ++i)
        op[(size_t)(c0 + ty + i * 8) * 1024 + r0 + tx] = f2bf(tile[tx][ty + i * 8]);
}

// ---------------- bf16 MFMA GEMM, counted-vmcnt pipeline -------------------
// 128x128 tile, BK=32, 4 waves x 64x64. Used for the N=1024 GEMMs (proj,
// FFN2) where a wider tile would drop the grid below 1 block/CU.
// v5 XCD remap + v8/v9 counted-vmcnt schedule + v10 superrow swizzle
// (SQ_LDS_BANK_CONFLICT 8.4M -> 0, verified round 10).
// EPI 0: fused QKV epilogue; EPI 2: fp32 +bias+resid; EPI 3: bf16 relu+bias
template <int EPI>
__global__ __launch_bounds__(256) void gemm_mfma(
    const short* __restrict__ A, const short* __restrict__ Bt,
    const float* __restrict__ bias, const float* __restrict__ resid,
    float* __restrict__ Cf, short* __restrict__ Cb0,
    short* __restrict__ Cb1, short* __restrict__ Cb2,
    int M, int N, int K, float scale)
{
    __shared__ short As[2][128 * 32];
    __shared__ short Bs[2][128 * 32];
    const int tid  = threadIdx.x;
    const int lane = tid & 63, wave = tid >> 6;
    const int quad = lane >> 4, l16 = lane & 15;

    const int lin = blockIdx.y * gridDim.x + blockIdx.x;
    const int xcd = lin & 7;
    const int s   = lin >> 3;
    const int my  = xcd * 8 + (s & 7);
    const int nx  = s >> 3;
    const int m0 = my * 128, n0 = nx * 128;

    const int wm = (wave >> 1) * 64, wn = (wave & 1) * 64;

    f32x4 acc[4][4];
#pragma unroll
    for (int i = 0; i < 4; ++i)
#pragma unroll
        for (int j = 0; j < 4; ++j) acc[i][j] = f32x4{0.f, 0.f, 0.f, 0.f};

    // v10 staging source swizzle (per-wave region of 32 rows)
    const int ssr = lane >> 3, sv = (lane & 7) ^ ssr;
    const int srow = ssr * 2 + (sv >> 2), sgr = sv & 3;
    const short* gA = A  + (size_t)(m0 + wave * 32 + srow) * K + sgr * 8;
    const short* gB = Bt + (size_t)(n0 + wave * 32 + srow) * K + sgr * 8;
    const size_t rstep = (size_t)16 * K;
    const int woff = wave * 1024;

    // v10 read swizzle: per-lane constant position offset (shorts)
    const int rofs = (l16 >> 1) * 64 +
        (((((l16 & 1) << 2) | quad) ^ ((l16 >> 1) & 7)) << 3);

    auto stageg = [&](int buf) {
        async_copy16(gA,         &As[buf][woff]);
        async_copy16(gA + rstep, &As[buf][woff + 512]);
        async_copy16(gB,         &Bs[buf][woff]);
        async_copy16(gB + rstep, &Bs[buf][woff + 512]);
        gA += 32; gB += 32;
    };

    stageg(0);
    stageg(1);

    const int ntile = K >> 5;
    int cur = 0;
    for (int t = 0; t < ntile; ++t) {
        if (t + 1 < ntile) asm volatile("s_waitcnt vmcnt(4)" ::: "memory");
        else               asm volatile("s_waitcnt vmcnt(0)" ::: "memory");
        __builtin_amdgcn_s_barrier();
        __builtin_amdgcn_sched_barrier(0);

        bf16x8 af[4], bfr[4];
#pragma unroll
        for (int mt = 0; mt < 4; ++mt)
            af[mt] = *(const bf16x8*)(&As[cur][(wm + mt * 16) * 32 + rofs]);
#pragma unroll
        for (int nt2 = 0; nt2 < 4; ++nt2)
            bfr[nt2] = *(const bf16x8*)(&Bs[cur][(wn + nt2 * 16) * 32 + rofs]);

        if (t + 2 < ntile) {
            asm volatile("s_waitcnt lgkmcnt(0)" ::: "memory");
            __builtin_amdgcn_sched_barrier(0);
            __builtin_amdgcn_s_barrier();
            __builtin_amdgcn_sched_barrier(0);
            stageg(cur);
        }

#pragma unroll
        for (int mt = 0; mt < 4; ++mt)
#pragma unroll
            for (int nt2 = 0; nt2 < 4; ++nt2)
                acc[mt][nt2] = __builtin_amdgcn_mfma_f32_16x16x32_bf16(
                    af[mt], bfr[nt2], acc[mt][nt2], 0, 0, 0);
        cur ^= 1;
    }

#pragma unroll
    for (int mt = 0; mt < 4; ++mt) {
#pragma unroll
        for (int nt2 = 0; nt2 < 4; ++nt2) {
#pragma unroll
            for (int r = 0; r < 4; ++r) {
                const int m = m0 + wm + mt * 16 + quad * 4 + r;
                const int c = n0 + wn + nt2 * 16 + l16;
                float val = acc[mt][nt2][r];
                if (EPI == 0) {
                    const int sel = c >> 10, cl = c & 1023;
                    if (sel == 0)
                        Cb0[headed_idx(m, cl)] = f2bf(val * scale);
                    else if (sel == 1)
                        Cb1[headed_idx(m, cl)] = f2bf(val);
                    else {
                        int b = m >> 11, t = m & 2047;
                        size_t idx = ((((size_t)((b << 4) | (cl >> 6)) << 6) | (cl & 63)) << 11) | t;
                        Cb2[idx] = f2bf(val);
                    }
                } else if (EPI == 2) {
                    size_t idx = (size_t)m * N + c;
                    Cf[idx] = val + bias[c] + resid[idx];
                } else {  // EPI 3
                    float v2 = val + bias[c];
                    Cb0[(size_t)m * N + c] = f2bf(v2 > 0.f ? v2 : 0.f);
                }
            }
        }
    }
}

// ---------------- wide-N bf16 MFMA GEMM (128x256 tile, BK=32) --------------
// v11: for the K=1024 wide-N GEMMs (QKV N=3072, FFN1 N=4096). Round-10
// post-mortem: the 64x64-per-wave shape reads 8 b128/16 MFMA = 96cy LDS vs
// 77cy MFMA per step -> LDS-read-throughput-bound (FFN1: 41us LDS floor vs
// 27.5us MFMA, measured 93us). 64x128 per wave (acc 4x8): 12 b128/32 MFMA
// = 144cy LDS vs 154cy MFMA -> MFMA-bound.
//   - Block 128x256, 4 waves (2m x 2n), LDS 48KB dbuf -> 2 blocks/CU
//     (VGPR ~200). Grid: QKV (12,64), FFN1 (16,64).
//   - Same v5 XCD remap (XCD owns 8 m-rows x all n; gridDim.y==64).
//   - Same v8/v9 counted-vmcnt protocol, 6 loads/thread/stage -> vmcnt(6).
//   - Same v10 superrow swizzle (block-wide staging: A 512 slots =
//     2/thread, B 1024 slots = 4/thread).
// v12 FIX (round-11 crash post-mortem): the FFN1 LAUNCH passed an extra
// nullptr, shifting ff1 out of the Cb0 slot -> EPI3 stored to nullptr ->
// device fault. Kernel body unchanged; launcher call arity corrected.
// EPI 0: fused QKV epilogue; EPI 3: bf16 relu(+bias).
template <int EPI>
__global__ __launch_bounds__(256) void gemm_wide(
    const short* __restrict__ A, const short* __restrict__ Bt,
    const float* __restrict__ bias,
    float* __restrict__ Cf, short* __restrict__ Cb0,
    short* __restrict__ Cb1, short* __restrict__ Cb2,
    int M, int N, int K, float scale)
{
    __shared__ short As[2][128 * 32];   // 2 x 8 KB
    __shared__ short Bs[2][256 * 32];   // 2 x 16 KB
    const int tid  = threadIdx.x;
    const int lane = tid & 63, wave = tid >> 6;
    const int quad = lane >> 4, l16 = lane & 15;

    const int lin = blockIdx.y * gridDim.x + blockIdx.x;
    const int xcd = lin & 7;
    const int s   = lin >> 3;
    const int my  = xcd * 8 + (s & 7);
    const int nx  = s >> 3;
    const int m0 = my * 128, n0 = nx * 256;

    const int wm = (wave >> 1) * 64, wn = (wave & 1) * 128;

    f32x4 acc[4][8];
#pragma unroll
    for (int i = 0; i < 4; ++i)
#pragma unroll
        for (int j = 0; j < 8; ++j) acc[i][j] = f32x4{0.f, 0.f, 0.f, 0.f};

    // block-wide staging with superrow swizzle: slot sl holds superrow
    // sr=sl>>3, pos q=sl&7 -> content row 2sr+(v>>2), gran v&3, v=q^(sr&7)
    const short* gAp[2];
    const short* gBp[4];
    int dA[2], dB[4];
#pragma unroll
    for (int i = 0; i < 2; ++i) {
        const int sl = tid + 256 * i, sr = sl >> 3, v = (sl & 7) ^ (sr & 7);
        gAp[i] = A + (size_t)(m0 + sr * 2 + (v >> 2)) * K + (v & 3) * 8;
        dA[i] = sl * 8;
    }
#pragma unroll
    for (int i = 0; i < 4; ++i) {
        const int sl = tid + 256 * i, sr = sl >> 3, v = (sl & 7) ^ (sr & 7);
        gBp[i] = Bt + (size_t)(n0 + sr * 2 + (v >> 2)) * K + (v & 3) * 8;
        dB[i] = sl * 8;
    }

    // read swizzle: per-lane constant position offset (shorts)
    const int rofs = (l16 >> 1) * 64 +
        (((((l16 & 1) << 2) | quad) ^ ((l16 >> 1) & 7)) << 3);

    auto stageg = [&](int buf) {
#pragma unroll
        for (int i = 0; i < 2; ++i) { async_copy16(gAp[i], &As[buf][dA[i]]); gAp[i] += 32; }
#pragma unroll
        for (int i = 0; i < 4; ++i) { async_copy16(gBp[i], &Bs[buf][dB[i]]); gBp[i] += 32; }
    };

    stageg(0);           // 6 loads in flight
    stageg(1);           // 12 in flight

    const int ntile = K >> 5;
    int cur = 0;
    for (int t = 0; t < ntile; ++t) {
        if (t + 1 < ntile) asm volatile("s_waitcnt vmcnt(6)" ::: "memory");
        else               asm volatile("s_waitcnt vmcnt(0)" ::: "memory");
        __builtin_amdgcn_s_barrier();
        __builtin_amdgcn_sched_barrier(0);   // pin ds_reads below barrier

        bf16x8 af[4], bfr[8];
#pragma unroll
        for (int mt = 0; mt < 4; ++mt)
            af[mt] = *(const bf16x8*)(&As[cur][(wm + mt * 16) * 32 + rofs]);
#pragma unroll
        for (int nt2 = 0; nt2 < 8; ++nt2)
            bfr[nt2] = *(const bf16x8*)(&Bs[cur][(wn + nt2 * 16) * 32 + rofs]);

        if (t + 2 < ntile) {
            asm volatile("s_waitcnt lgkmcnt(0)" ::: "memory");
            __builtin_amdgcn_sched_barrier(0);
            __builtin_amdgcn_s_barrier();        // all waves done reading cur
            __builtin_amdgcn_sched_barrier(0);   // pin stage below barrier
            stageg(cur);                         // tile t+2 -> buf[cur]
        }

#pragma unroll
        for (int mt = 0; mt < 4; ++mt)
#pragma unroll
            for (int nt2 = 0; nt2 < 8; ++nt2)
                acc[mt][nt2] = __builtin_amdgcn_mfma_f32_16x16x32_bf16(
                    af[mt], bfr[nt2], acc[mt][nt2], 0, 0, 0);
        cur ^= 1;
    }

#pragma unroll
    for (int mt = 0; mt < 4; ++mt) {
#pragma unroll
        for (int nt2 = 0; nt2 < 8; ++nt2) {
#pragma unroll
            for (int r = 0; r < 4; ++r) {
                const int m = m0 + wm + mt * 16 + quad * 4 + r;
                const int c = n0 + wn + nt2 * 16 + l16;
                float val = acc[mt][nt2][r];
                if (EPI == 0) {
                    const int sel = c >> 10, cl = c & 1023;
                    if (sel == 0)
                        Cb0[headed_idx(m, cl)] = f2bf(val * scale);
                    else if (sel == 1)
                        Cb1[headed_idx(m, cl)] = f2bf(val);
                    else {
                        int b = m >> 11, t = m & 2047;
                        size_t idx = ((((size_t)((b << 4) | (cl >> 6)) << 6) | (cl & 63)) << 11) | t;
                        Cb2[idx] = f2bf(val);
                    }
                } else {  // EPI 3
                    float v2 = val + bias[c];
                    Cb0[(size_t)m * N + c] = f2bf(v2 > 0.f ? v2 : 0.f);
                }
            }
        }
    }
}

// ---------------- MFMA flash attention, LDS-staged K/V ---------------------
// v4 (round-6 passing version, unchanged): tile-pair balance, XCD
// clustering, 40KB LDS, 4 blocks/CU, __syncthreads-based 2-phase pipeline.
// S^T = K Q^T (A=K-frag, B=Q-frag) so each lane owns ONE query row (l16):
//   - P packed via v_perm -> ds_write_b64 (4 writes/chunk, XOR-swizzled)
//   - row-sum l is a per-lane scalar (2 shfls per tile at the end)
// PV computes O^T (A=V^T-frag, B=P from LDS). No-max softmax via exp2
// (Q pre-scaled by HD^-0.5 * log2 e). Output bf16 row-major (head concat).
__global__ __launch_bounds__(256, 4) void fattn_kernel(
    const short* __restrict__ Q,
    const short* __restrict__ K,
    const short* __restrict__ VT,
    short* __restrict__ O)
{
    __shared__ short Kl[2][64 * 64];
    __shared__ short Vl[2][64 * 64];
    __shared__ short p_lds[4][16 * 64];
    const int tid  = threadIdx.x;
    const int lane = tid & 63, wave = tid >> 6;
    const int quad = lane >> 4, l16 = lane & 15;

    // XCD-clustered remap (bijective): lin%8 = XCD under round-robin
    // dispatch; all 16 tile-pair blocks of one bh share one XCD.
    const int lin  = blockIdx.y * 16 + blockIdx.x;   // 0..1023
    const int xcd  = lin & 7;
    const int slot = lin >> 3;                       // 0..127
    const int bh   = xcd * 8 + (slot >> 4);          // 0..63
    const int px   = slot & 15;                      // 0..15
    const int tiles[2] = { 31 - px, px };            // heavy tile first

    const int bb = bh >> 4, hh = bh & 15;
    const size_t bhoff = (size_t)bh * (Tsz * HDs);
    const short* Qb = Q + bhoff;
    const short* Kb = K + bhoff;
    const short* Vb = VT + bhoff;

    // staging: 512 slots of 16B per 64x64 tile, 2 rounds of 256 threads.
    // slot s: row = s>>3, granule = s&7; fetch source granule (s&7)^(row&7)
    const int s_a = tid, s_b = tid + 256;
    const int ra = s_a >> 3, ga = (s_a & 7) ^ (ra & 7);
    const int rb = s_b >> 3, gb = (s_b & 7) ^ (rb & 7);

    short* pw = &p_lds[wave][0];
    // swizzled read offsets (shorts): granule g stored at g^(l16&7)
    const int rd0 = l16 * 64 + (((quad    ) ^ (l16 & 7)) << 3);
    const int rd1 = l16 * 64 + (((quad + 4) ^ (l16 & 7)) << 3);

    // Q B-fragments for both tiles upfront: lane n = query row l16, k = d
    bf16x8 bq[2][2];
#pragma unroll
    for (int ti = 0; ti < 2; ++ti) {
        const short* qp = Qb + (size_t)(tiles[ti] * 64 + wave * 16 + l16) * 64 + quad * 8;
        bq[ti][0] = *(const bf16x8*)qp;
        bq[ti][1] = *(const bf16x8*)(qp + 32);
    }

    auto stage = [&](int c64, int buf) {
        short* kb_l = &Kl[buf][0];
        short* vb_l = &Vl[buf][0];
        async_copy16(Kb + (((size_t)(c64 + ra)) << 6) + (ga << 3), kb_l + s_a * 8);
        async_copy16(Kb + (((size_t)(c64 + rb)) << 6) + (gb << 3), kb_l + s_b * 8);
        async_copy16(Vb + ((size_t)ra << 11) + c64 + (ga << 3), vb_l + s_a * 8);
        async_copy16(Vb + ((size_t)rb << 11) + c64 + (gb << 3), vb_l + s_b * 8);
    };

    stage(tiles[0] * 0, 0);     // tile A chunk 0
    __syncthreads();            // compiler drains vmcnt before s_barrier

    int phase = 0;
#pragma unroll
    for (int ti = 0; ti < 2; ++ti) {
        const int tile = tiles[ti];
        const int q0w  = tile * 64 + wave * 16;   // wave's first query row
        const int nch  = tile + 1;

        f32x4 oaccT[4];
        float lacc = 0.f;
#pragma unroll
        for (int nt = 0; nt < 4; ++nt) oaccT[nt] = f32x4{0.f, 0.f, 0.f, 0.f};

        for (int c = 0; c < nch; ++c) {
            const int cur = phase & 1;
            if (c + 1 < nch)   stage((c + 1) * 64, cur ^ 1);
            else if (ti == 0)  stage(0, cur ^ 1);    // tile B chunk 0

            const int s0 = c * 64;
            const short* Kc = &Kl[cur][0];
            const short* Vc = &Vl[cur][0];
            // ---- K / V^T A-fragments from LDS (swizzled, balanced b128) ----
            bf16x8 ak[4][2], av[4][2];
#pragma unroll
            for (int ct = 0; ct < 4; ++ct) {
                const int r = ct * 16 + l16;
                ak[ct][0] = *(const bf16x8*)(Kc + r * 64 + (((quad    ) ^ (r & 7)) << 3));
                ak[ct][1] = *(const bf16x8*)(Kc + r * 64 + (((quad + 4) ^ (r & 7)) << 3));
            }
#pragma unroll
            for (int nt = 0; nt < 4; ++nt) {
                const int r = nt * 16 + l16;
                av[nt][0] = *(const bf16x8*)(Vc + r * 64 + (((quad    ) ^ (r & 7)) << 3));
                av[nt][1] = *(const bf16x8*)(Vc + r * 64 + (((quad + 4) ^ (r & 7)) << 3));
            }
            // ---- S^T = K Q^T : D col = query row (l16), row = key pos ----
            f32x4 sfr[4];
#pragma unroll
            for (int ct = 0; ct < 4; ++ct) {
                f32x4 cc = {0.f, 0.f, 0.f, 0.f};
                cc = __builtin_amdgcn_mfma_f32_16x16x32_bf16(ak[ct][0], bq[ti][0], cc, 0, 0, 0);
                cc = __builtin_amdgcn_mfma_f32_16x16x32_bf16(ak[ct][1], bq[ti][1], cc, 0, 0, 0);
                sfr[ct] = cc;
            }
            // ---- causal mask (only the diagonal chunk) ----
            if (s0 + 63 > q0w) {
                const int qr = q0w + l16;
#pragma unroll
                for (int ct = 0; ct < 4; ++ct)
#pragma unroll
                    for (int r = 0; r < 4; ++r)
                        if (s0 + ct * 16 + quad * 4 + r > qr)
                            sfr[ct][r] = -INFINITY;
            }
            // ---- P = exp2(S); scalar row-sum; packed b64 LDS writes ----
#pragma unroll
            for (int ct = 0; ct < 4; ++ct) {
                float p0 = __builtin_exp2f(sfr[ct][0]);
                float p1 = __builtin_exp2f(sfr[ct][1]);
                float p2 = __builtin_exp2f(sfr[ct][2]);
                float p3 = __builtin_exp2f(sfr[ct][3]);
                lacc += (p0 + p1) + (p2 + p3);
                uint2 pkv;
                pkv.x = pack_bf16(p1, p0);
                pkv.y = pack_bf16(p3, p2);
                const int g = (2 * ct + (quad >> 1)) ^ (l16 & 7);
                *(uint2*)(pw + l16 * 64 + (g << 3) + (quad & 1) * 4) = pkv;
            }
            // ---- P back as B-fragments (balanced b128 reads) ----
            bf16x8 bp0 = *(const bf16x8*)(pw + rd0);
            bf16x8 bp1 = *(const bf16x8*)(pw + rd1);
            // ---- O^T += V^T P^T : D col = query row, row = head dim ----
#pragma unroll
            for (int nt = 0; nt < 4; ++nt) {
                oaccT[nt] = __builtin_amdgcn_mfma_f32_16x16x32_bf16(av[nt][0], bp0, oaccT[nt], 0, 0, 0);
                oaccT[nt] = __builtin_amdgcn_mfma_f32_16x16x32_bf16(av[nt][1], bp1, oaccT[nt], 0, 0, 0);
            }
            __syncthreads();   // next stage drained; all waves done with cur
            ++phase;
        }

        // ---- finalize tile: reduce l across quads, normalize, store ----
        float ps = lacc;
        ps += __shfl_xor(ps, 16);
        ps += __shfl_xor(ps, 32);
        const float inv = 1.f / ps;
        short* orow = O + (size_t)(bb * Tsz + q0w + l16) * Dsz + hh * 64;
#pragma unroll
        for (int nt = 0; nt < 4; ++nt) {
            uint2 pkv;
            pkv.x = pack_bf16(oaccT[nt][1] * inv, oaccT[nt][0] * inv);
            pkv.y = pack_bf16(oaccT[nt][3] * inv, oaccT[nt][2] * inv);
            *(uint2*)(orow + nt * 16 + quad * 4) = pkv;
        }
    }
}

extern "C" void kernel_launch(void* const* d_in, const int* in_sizes, int n_in,
                              void* d_out, int out_size, void* d_ws, size_t ws_size,
                              hipStream_t stream) {
    const float* x   = (const float*)d_in[0];
    const float* Wq  = (const float*)d_in[1];
    const float* Wk  = (const float*)d_in[2];
    const float* Wv  = (const float*)d_in[3];
    const float* Wp  = (const float*)d_in[4];
    const float* bp  = (const float*)d_in[5];
    const float* W1  = (const float*)d_in[6];
    const float* b1  = (const float*)d_in[7];
    const float* W2  = (const float*)d_in[8];
    const float* b2  = (const float*)d_in[9];
    const float* g1  = (const float*)d_in[10];
    const float* be1 = (const float*)d_in[11];
    const float* g2  = (const float*)d_in[12];
    const float* be2 = (const float*)d_in[13];
    float* out = (float*)d_out;
    char*  W   = (char*)d_ws;

    short* h1  = (short*)(W);
    short* ff1 = (short*)(W);
    short* qb  = (short*)(W + (16ull << 20));
    short* kb  = (short*)(W + (32ull << 20));
    short* vtb = (short*)(W + (48ull << 20));
    short* o   = (short*)(W + (64ull << 20));
    short* h2  = (short*)(W + (80ull << 20));
    short* wqt = (short*)(W + (96ull << 20));
    short* wpt = (short*)(W + (102ull << 20));
    short* w1t = (short*)(W + (104ull << 20));
    short* w2t = (short*)(W + (112ull << 20));

    const int M = Bsz * Tsz;  // 8192
    // Q scale folds softmax's HD^-0.5 and exp->exp2 conversion (log2 e).
    const float qscale = 0.125f * 1.44269504f;

    transpose_cvt_qkv<<<dim3(2, 32, 48), 256, 0, stream>>>(Wq, Wk, Wv, wqt);
    transpose_cvt<<<dim3(32, 32, 1),  256, 0, stream>>>(Wp, wpt, 1024, 1024);
    transpose_cvt<<<dim3(128, 32, 1), 256, 0, stream>>>(W1, w1t, 1024, 4096);
    transpose_cvt<<<dim3(32, 128, 1), 256, 0, stream>>>(W2, w2t, 4096, 1024);

    ln_kernel<<<dim3(M), 256, 0, stream>>>(x, g1, be1, h1);

    gemm_wide<0><<<dim3(12, 64), 256, 0, stream>>>(
        h1, wqt, nullptr, nullptr, qb, kb, vtb, M, 3072, 1024, qscale);

    fattn_kernel<<<dim3(16, Bsz * Hn), 256, 0, stream>>>(qb, kb, vtb, o);

    gemm_mfma<2><<<dim3(8, 64), 256, 0, stream>>>(
        o, wpt, bp, x, out, nullptr, nullptr, nullptr, M, 1024, 1024, 1.f);

    ln_kernel<<<dim3(M), 256, 0, stream>>>(out, g2, be2, h2);

    gemm_wide<3><<<dim3(16, 64), 256, 0, stream>>>(
        h2, w1t, b1, nullptr, ff1, nullptr, nullptr, M, 4096, 1024, 1.f);

    gemm_mfma<2><<<dim3(8, 64), 256, 0, stream>>>(
        ff1, w2t, b2, out, out, nullptr, nullptr, nullptr, M, 1024, 4096, 1.f);
}